// Round 1
// 63.024 us; speedup vs baseline: 1.0160x; 1.0160x over previous
//
#include <hip/hip_runtime.h>

// CurveGraphic2d: render 16 cubic Beziers onto 256x256 canvases.
// Output [16,256,256] float32.
// v3: barrier-free, LDS-free. Every wave redundantly rebuilds the 32 curve
// samples entirely in registers: Bernstein eval per lane, arc length via
// __shfl_down segments + __shfl_xor butterfly reduce, de Casteljau left
// subdivision computed uniformly on all lanes. Tile prune via in-wave
// __ballot (wave-uniform). Min-distance loop broadcasts samples with
// v_readlane (SGPR operands), so there is no LDS and no __syncthreads
// anywhere — the old version's serial thread-0 arc-length chain (~1000
// dependent cycles) and 3 barriers were the per-block critical path.

constexpr int CH = 256, CW = 256;   // canvas
constexpr int S = 32;               // NUM_SAMPLES
constexpr int NB = 16;              // batch
constexpr int BLK = 256;            // threads/block
constexpr int TILE = 32;            // tile is 32x32 px, 4 px/thread in x
constexpr float MAXLEN = 300.0f;
constexpr float EPS = 1e-6f;

__device__ inline void bez4v(const float cy[4], const float cx[4], float t,
                             float& ry, float& rx) {
    float u = 1.0f - t;
    float b0 = u * u * u;
    float b1 = 3.0f * u * u * t;
    float b2 = 3.0f * u * t * t;
    float b3 = t * t * t;
    ry = b0 * cy[0] + b1 * cy[1] + b2 * cy[2] + b3 * cy[3];
    rx = b0 * cx[0] + b1 * cx[1] + b2 * cx[2] + b3 * cx[3];
}

__device__ inline float shade(float m, float wd, float aa) {
    float md = sqrtf(m);                 // min over d^2 == (min over d)^2
    float base = md / wd + EPS;
    float v = 1.0f - __expf(aa * __logf(base));   // base > 0 always
    return fminf(fmaxf(v, 0.0f), 1.0f);
}

__global__ __launch_bounds__(BLK) void curve_kernel(
    const float* __restrict__ inp,     // [16,4,2] normalized keypoints
    const float* __restrict__ widths,  // [16]
    const float* __restrict__ aas,     // [16]
    float* __restrict__ out)           // [16,256,256]
{
    const int b = blockIdx.z;
    const int tx0 = blockIdx.x * TILE;   // tile col origin
    const int ty0 = blockIdx.y * TILE;   // tile row origin
    const int tid = threadIdx.x;
    const int sj = tid & 31;             // sample index this lane owns
                                         // (lanes 32..63 mirror 0..31)

    // ---- control points (wave-uniform address -> scalar loads) ----
    float cy[4], cx[4];
#pragma unroll
    for (int k = 0; k < 4; ++k) {
        cy[k] = inp[(b * 4 + k) * 2 + 0] * 256.0f;  // y (scaled by H)
        cx[k] = inp[(b * 4 + k) * 2 + 1] * 256.0f;  // x (scaled by W)
    }
    const float wd = widths[b];

    // ---- initial sample at t = sj/31, per lane ----
    const float t = (float)sj * (1.0f / 31.0f);
    float py, px;
    bez4v(cy, cx, t, py, px);

    // ---- arc length: per-lane segment + full-wave butterfly sum ----
    float nyy = __shfl_down(py, 1);
    float nxx = __shfl_down(px, 1);
    float dsy = nyy - py, dsx = nxx - px;
    float seg = (sj < 31) ? sqrtf(dsy * dsy + dsx * dsx) : 0.0f;
#pragma unroll
    for (int m = 1; m < 64; m <<= 1) seg += __shfl_xor(seg, m);
    const float arc = 0.5f * seg;        // both 32-lane halves hold a copy

    // ---- de Casteljau left subdivision (uniform on all lanes) ----
    const float tt = fminf(1.0f, MAXLEN / (arc + EPS));
    const float u = 1.0f - tt;
    float a01y = u * cy[0] + tt * cy[1], a01x = u * cx[0] + tt * cx[1];
    float a12y = u * cy[1] + tt * cy[2], a12x = u * cx[1] + tt * cx[2];
    float a23y = u * cy[2] + tt * cy[3], a23x = u * cx[2] + tt * cx[3];
    float q0y = u * a01y + tt * a12y,   q0x = u * a01x + tt * a12x;
    float q1y = u * a12y + tt * a23y,   q1x = u * a12x + tt * a23x;
    float c0y = u * q0y + tt * q1y,     c0x = u * q0x + tt * q1x;
    float ly[4] = { cy[0], a01y, q0y, c0y };
    float lx[4] = { cx[0], a01x, q0x, c0x };

    // ---- final sample (truncated curve) for this lane ----
    float spy, spx;
    bez4v(ly, lx, t, spy, spx);

    // ---- tile prune: exact-zero test (min_d >= w -> pixel value 0) ----
    // continuous rect-distance lower bound (spy = y-coord, spx = x-coord)
    float dyl = fmaxf(0.0f, fmaxf((float)ty0 - spy, spy - (float)(ty0 + TILE - 1)));
    float dxl = fmaxf(0.0f, fmaxf((float)tx0 - spx, spx - (float)(tx0 + TILE - 1)));
    bool pred = fmaf(dxl, dxl, dyl * dyl) < wd * wd;
    unsigned long long mask = __ballot(pred);  // wave-uniform, identical per wave

    // thread -> pixel mapping: 4 consecutive px in x; 8 col-groups x 32 rows
    const int row = ty0 + (tid >> 3);
    const int col = tx0 + (tid & 7) * 4;
    float* dst = out + b * (CH * CW) + row * CW + col;

    if (mask == 0ULL) {
        *reinterpret_cast<float4*>(dst) = make_float4(0.0f, 0.0f, 0.0f, 0.0f);
        return;
    }

    // ---- active tile: min over 32 samples of squared distance ----
    // Samples live in lane registers; broadcast lane j via v_readlane
    // (literal lane index after unroll -> SGPR operand, no LDS).
    const float aa = aas[b];
    const float fy = (float)row;
    const float fx = (float)col;

    float m0 = 1e30f, m1 = 1e30f, m2 = 1e30f, m3 = 1e30f;
#pragma unroll
    for (int j = 0; j < S; ++j) {
        float sy = __uint_as_float(
            (unsigned)__builtin_amdgcn_readlane((int)__float_as_uint(spy), j));
        float sx = __uint_as_float(
            (unsigned)__builtin_amdgcn_readlane((int)__float_as_uint(spx), j));
        float dy  = fy - sy;
        float dy2 = dy * dy;
        float dx0 = fx - sx;
        float dx1 = fx + 1.0f - sx;
        float dx2 = fx + 2.0f - sx;
        float dx3 = fx + 3.0f - sx;
        m0 = fminf(m0, fmaf(dx0, dx0, dy2));
        m1 = fminf(m1, fmaf(dx1, dx1, dy2));
        m2 = fminf(m2, fmaf(dx2, dx2, dy2));
        m3 = fminf(m3, fmaf(dx3, dx3, dy2));
    }

    float4 o;
    o.x = shade(m0, wd, aa);
    o.y = shade(m1, wd, aa);
    o.z = shade(m2, wd, aa);
    o.w = shade(m3, wd, aa);
    *reinterpret_cast<float4*>(dst) = o;
}

extern "C" void kernel_launch(void* const* d_in, const int* in_sizes, int n_in,
                              void* d_out, int out_size, void* d_ws, size_t ws_size,
                              hipStream_t stream) {
    const float* inp = (const float*)d_in[0];     // [16,4,2]
    const float* widths = (const float*)d_in[1];  // [16]
    const float* aas = (const float*)d_in[2];     // [16]
    float* out = (float*)d_out;                   // [16,256,256]

    dim3 grid(CW / TILE, CH / TILE, NB);          // (8, 8, 16)
    curve_kernel<<<grid, BLK, 0, stream>>>(inp, widths, aas, out);
}